// Round 8
// baseline (1567.391 us; speedup 1.0000x reference)
//
#include <hip/hip_runtime.h>

#define NN 64
#define KK 16
#define HC 32   // A-columns per wave
#define HK 8    // b-columns per wave

// Broadcast a float from a (wave-uniform) lane: v_readlane -> SGPR operand.
__device__ __forceinline__ float rlane(float v, int l) {
  return __int_as_float(__builtin_amdgcn_readlane(__float_as_int(v), l));
}

// Wave64 argmax via DPP (VALU-rate). key: u32 whose order = priority.
__device__ __forceinline__ unsigned dpp_argmax64(unsigned key) {
  unsigned t;
  t = (unsigned)__builtin_amdgcn_update_dpp(0, (int)key, 0x111, 0xf, 0xf, true);
  key = key > t ? key : t;
  t = (unsigned)__builtin_amdgcn_update_dpp(0, (int)key, 0x112, 0xf, 0xf, true);
  key = key > t ? key : t;
  t = (unsigned)__builtin_amdgcn_update_dpp(0, (int)key, 0x114, 0xf, 0xf, true);
  key = key > t ? key : t;
  t = (unsigned)__builtin_amdgcn_update_dpp(0, (int)key, 0x118, 0xf, 0xf, true);
  key = key > t ? key : t;
  t = (unsigned)__builtin_amdgcn_update_dpp(0, (int)key, 0x142, 0xf, 0xf, true);
  key = key > t ? key : t;
  t = (unsigned)__builtin_amdgcn_update_dpp(0, (int)key, 0x143, 0xf, 0xf, true);
  key = key > t ? key : t;
  return (unsigned)__builtin_amdgcn_readlane((int)key, 63);
}

// 2 waves per batch (block = 128). Lane = row. Wave w owns A-columns
// {w, w+2, ..., w+62} (parity interleave -> balanced shrink) and b-columns
// [8w, 8w+8). Per-wave register state: 80 floats + temps.
//
// THIS ROUND'S ONLY CHANGE vs the round-5 PASSING kernel:
// launch_bounds(128,2) -> waves_per_eu(2,2). Round-5 evidence: launch_bounds'
// 2nd arg is a MIN-occupancy floor, so the allocator targeted 4 waves/EU
// (128-reg budget), overflowed, and demoted the arrays to scratch (1.3 GB of
// stack traffic, VALUBusy 46%). Round-7 evidence: amdgpu_waves_per_eu pins
// the budget cleanly (scratch-free). (2,2) => 256-reg budget per wave; the
// ~150-190-reg demand fits entirely in ARCH VGPRs: no scratch, no AGPR
// split, 2 waves/SIMD.
//
// p is re-uniformed with readfirstlane AFTER the owner/non-owner merge:
// `w == owner` is divergent to the compiler, so the merged p would otherwise
// be a divergent value and every readlane(C[j], p) would waterfall.
//
// Rotation trick per wave: a wave rotates its columns left by one slot only
// on steps where it owns the current column, so the current column is always
// the owner's slot 0 and all register indices are compile-time constants.
//
// Per step: owner computes pivot p (DPP argmax) + per-row multiplier m,
// publishes {m[64], p, 1/pivot} via double-buffered LDS (buffer = step
// parity), one __syncthreads(), both waves update their own columns.
// Read@k and the next write@k+2 of the same buffer are separated by
// barrier@k+1 -> race-free with a single barrier per step.
__global__ void __launch_bounds__(128)
__attribute__((amdgpu_waves_per_eu(2, 2)))
cgj_solve(const float* __restrict__ A_r, const float* __restrict__ A_i,
          const float* __restrict__ b_r, const float* __restrict__ b_i,
          float* __restrict__ out, int nbatch) {
  const int batch = blockIdx.x;
  const int w     = threadIdx.x >> 6;   // wave id: 0/1
  const int lane  = threadIdx.x & 63;   // row

  __shared__ float2 mbuf[2][64];  // per-row multiplier, double-buffered
  __shared__ float4 hdr[2];       // {ip_re, ip_im, bits(p), 0}

  float Cr[HC], Ci[HC], Br[HK], Bi[HK];

  // ---- load: lane reads its full row, keeps parity-w columns ----
  const size_t abase = (size_t)batch * NN * NN + (size_t)lane * NN;
  const float4* pAr = reinterpret_cast<const float4*>(A_r + abase);
  const float4* pAi = reinterpret_cast<const float4*>(A_i + abase);
#pragma unroll
  for (int j = 0; j < 16; ++j) {
    float4 v = pAr[j];                  // cols 4j .. 4j+3
    Cr[2*j]   = w ? v.y : v.x;
    Cr[2*j+1] = w ? v.w : v.z;
  }
#pragma unroll
  for (int j = 0; j < 16; ++j) {
    float4 v = pAi[j];
    Ci[2*j]   = w ? v.y : v.x;
    Ci[2*j+1] = w ? v.w : v.z;
  }
  const size_t bbase = (size_t)batch * NN * KK + (size_t)lane * KK + (size_t)(HK * w);
  const float4* pbr = reinterpret_cast<const float4*>(b_r + bbase);
  const float4* pbi = reinterpret_cast<const float4*>(b_i + bbase);
#pragma unroll
  for (int j = 0; j < HK / 4; ++j) {
    float4 v = pbr[j];
    Br[4*j+0] = v.x; Br[4*j+1] = v.y; Br[4*j+2] = v.z; Br[4*j+3] = v.w;
    float4 u = pbi[j];
    Bi[4*j+0] = u.x; Bi[4*j+1] = u.y; Bi[4*j+2] = u.z; Bi[4*j+3] = u.w;
  }

  float invd_re = 0.f, invd_im = 0.f;
  int   mystep  = 0;
  bool  done    = false;

  for (int k = 0; k < NN; ++k) {
    const int owner = k & 1;
    float m_re, m_im;
    int   p_loc;

    if (w == owner) {
      // ---- pivot: DPP argmax of |slot0|^2, lane idx in low 6 bits ----
      const float sc = Cr[0]*Cr[0] + Ci[0]*Ci[0];
      unsigned key = done ? (unsigned)lane
                          : ((__float_as_uint(sc) & ~63u) | (unsigned)lane);
      const int p = (int)(dpp_argmax64(key) & 63u);
      const float p_re = rlane(Cr[0], p);
      const float p_im = rlane(Ci[0], p);
      const float d    = p_re*p_re + p_im*p_im;
      float rd = __builtin_amdgcn_rcpf(d);
      rd = rd * (2.0f - d * rd);
      const float ip_re =  p_re * rd;
      const float ip_im = -p_im * rd;
      m_re = Cr[0]*ip_re - Ci[0]*ip_im;
      m_im = Cr[0]*ip_im + Ci[0]*ip_re;
      if (lane == p) {
        m_re = 0.f; m_im = 0.f;
        invd_re = ip_re; invd_im = ip_im;
        mystep = k; done = true;
      }
      mbuf[owner][lane] = float2{m_re, m_im};
      if (lane == 0)
        hdr[owner] = float4{ip_re, ip_im, __uint_as_float((unsigned)p), 0.f};
      p_loc = p;
    }
    __syncthreads();
    if (w != owner) {
      const float2 mv = mbuf[owner][lane];
      const float4 h  = hdr[owner];
      m_re = mv.x; m_im = mv.y;
      p_loc = (int)__float_as_uint(h.z);
      if (lane == p_loc) {
        invd_re = h.x; invd_im = h.y;
        mystep = k; done = true;
      }
    }
    // Re-uniform p: the w==owner branch is divergent to the compiler, so the
    // merged value would otherwise be divergent -> readlane waterfalls.
    const int p = __builtin_amdgcn_readfirstlane(p_loc);

    // ---- A update (own columns, static indices, 8-block dead skipping) ----
    if (w == owner) {
      // live slots 0..(31 - k/2); eliminate slot 0, rotate 1..hi -> 0..hi-1
      const int hi = 31 - (k >> 1);
#pragma unroll
      for (int blk = 0; blk < 4; ++blk) {
        const int j0 = (blk == 0) ? 1 : 8 * blk;
        if (hi >= j0) {
#pragma unroll
          for (int j = j0; j < 8 * (blk + 1); ++j) {
            const float sr = rlane(Cr[j], p);
            const float si = rlane(Ci[j], p);
            Cr[j-1] = __builtin_fmaf(-m_re, sr, __builtin_fmaf( m_im, si, Cr[j]));
            Ci[j-1] = __builtin_fmaf(-m_im, sr, __builtin_fmaf(-m_re, si, Ci[j]));
          }
        }
      }
    } else {
      // live slots 0..(31 - (k+1)/2), update in place
      const int hi = 31 - ((k + 1) >> 1);
#pragma unroll
      for (int blk = 0; blk < 4; ++blk) {
        if (hi >= 8 * blk) {
#pragma unroll
          for (int j = 8 * blk; j < 8 * (blk + 1); ++j) {
            const float sr = rlane(Cr[j], p);
            const float si = rlane(Ci[j], p);
            Cr[j] = __builtin_fmaf(-m_re, sr, __builtin_fmaf( m_im, si, Cr[j]));
            Ci[j] = __builtin_fmaf(-m_im, sr, __builtin_fmaf(-m_re, si, Ci[j]));
          }
        }
      }
    }

    // ---- b update (own 8 columns, both waves) ----
#pragma unroll
    for (int c = 0; c < HK; ++c) {
      const float sr = rlane(Br[c], p);
      const float si = rlane(Bi[c], p);
      Br[c] = __builtin_fmaf(-m_re, sr, __builtin_fmaf( m_im, si, Br[c]));
      Bi[c] = __builtin_fmaf(-m_im, sr, __builtin_fmaf(-m_re, si, Bi[c]));
    }
  }

  // ---- x[mystep][c] = b[c] * invd ; lane writes its row, own 8 columns ----
  float xr[HK], xi[HK];
#pragma unroll
  for (int c = 0; c < HK; ++c) {
    xr[c] = Br[c]*invd_re - Bi[c]*invd_im;
    xi[c] = Br[c]*invd_im + Bi[c]*invd_re;
  }
  const size_t obase = (size_t)batch * NN * KK + (size_t)mystep * KK + (size_t)(HK * w);
  float* o_r = out + obase;
  float* o_i = out + (size_t)nbatch * NN * KK + obase;
#pragma unroll
  for (int j = 0; j < HK / 4; ++j) {
    float4 v;
    v.x = xr[4*j+0]; v.y = xr[4*j+1]; v.z = xr[4*j+2]; v.w = xr[4*j+3];
    reinterpret_cast<float4*>(o_r)[j] = v;
    float4 u;
    u.x = xi[4*j+0]; u.y = xi[4*j+1]; u.z = xi[4*j+2]; u.w = xi[4*j+3];
    reinterpret_cast<float4*>(o_i)[j] = u;
  }
}

extern "C" void kernel_launch(void* const* d_in, const int* in_sizes, int n_in,
                              void* d_out, int out_size, void* d_ws, size_t ws_size,
                              hipStream_t stream) {
  const float* A_r = (const float*)d_in[0];
  const float* A_i = (const float*)d_in[1];
  const float* b_r = (const float*)d_in[2];
  const float* b_i = (const float*)d_in[3];
  float* out = (float*)d_out;
  const int nbatch = in_sizes[0] / (NN * NN);  // 8192
  cgj_solve<<<nbatch, 128, 0, stream>>>(A_r, A_i, b_r, b_i, out, nbatch);
}

// Round 9
// 484.585 us; speedup vs baseline: 3.2345x; 3.2345x over previous
//
#include <hip/hip_runtime.h>

#define NN 64
#define KK 16
#define NW 4    // waves per batch
#define HC 16   // A-columns per wave
#define HK 4    // b-columns per wave

// Broadcast a float from a (wave-uniform) lane: v_readlane -> SGPR operand.
__device__ __forceinline__ float rlane(float v, int l) {
  return __int_as_float(__builtin_amdgcn_readlane(__float_as_int(v), l));
}

// Wave64 argmax via DPP (VALU-rate). key: u32 whose order = priority.
__device__ __forceinline__ unsigned dpp_argmax64(unsigned key) {
  unsigned t;
  t = (unsigned)__builtin_amdgcn_update_dpp(0, (int)key, 0x111, 0xf, 0xf, true);
  key = key > t ? key : t;
  t = (unsigned)__builtin_amdgcn_update_dpp(0, (int)key, 0x112, 0xf, 0xf, true);
  key = key > t ? key : t;
  t = (unsigned)__builtin_amdgcn_update_dpp(0, (int)key, 0x114, 0xf, 0xf, true);
  key = key > t ? key : t;
  t = (unsigned)__builtin_amdgcn_update_dpp(0, (int)key, 0x118, 0xf, 0xf, true);
  key = key > t ? key : t;
  t = (unsigned)__builtin_amdgcn_update_dpp(0, (int)key, 0x142, 0xf, 0xf, true);
  key = key > t ? key : t;
  t = (unsigned)__builtin_amdgcn_update_dpp(0, (int)key, 0x143, 0xf, 0xf, true);
  key = key > t ? key : t;
  return (unsigned)__builtin_amdgcn_readlane((int)key, 63);
}

// 4 waves per batch (block = 256). Lane = row. Wave w owns A-columns
// {w, w+4, ..., w+60} (mod-4 interleave -> balanced shrink) and b-columns
// [4w, 4w+4). Per-wave array state: 16+16+4+4 = 40 floats (~70-100 regs
// total) -- the point of this round. Rounds 3/5/7/8 established that the
// allocator caps arch VGPRs at ~128-132 for this kernel no matter what
// attribute is applied, sending overflow to AGPRs (move tax, R3/R7) or
// scratch (R5/R8). 40 floats/wave fits comfortably under 128 arch VGPRs at
// DEFAULT settings: no AGPR, no scratch, high occupancy. No launch-bounds
// min-waves promise, no waves_per_eu -- unconstrained never scratched.
//
// Step machinery is exactly the round-5 PROVEN-CORRECT pattern (only the
// modulus changes 2->4): owner computes pivot p (DPP argmax) + per-row
// multiplier m, publishes {m[64], p, 1/pivot} via LDS double-buffered by
// step parity, one __syncthreads(), p re-uniformed with readfirstlane after
// the divergent owner/non-owner merge. Read@k and next write@k+2 of a
// buffer are separated by barrier@k+1 -> race-free with 1 barrier/step.
//
// Rotation trick per wave: the owner rotates its columns left by one slot
// on its own steps, so the current column is always the owner's slot 0 and
// all register indices are compile-time constants. Wave w's eliminated-
// column count before step k: e_w(k) = (k>w) ? (k-w+3)>>2 : 0; live slots
// are 0..15-e.
__global__ void __launch_bounds__(256)
cgj_solve(const float* __restrict__ A_r, const float* __restrict__ A_i,
          const float* __restrict__ b_r, const float* __restrict__ b_i,
          float* __restrict__ out, int nbatch) {
  const int batch = blockIdx.x;
  const int w     = threadIdx.x >> 6;   // wave id: 0..3
  const int lane  = threadIdx.x & 63;   // row

  __shared__ float2 mbuf[2][64];  // per-row multiplier, dbuf by step parity
  __shared__ float4 hdr[2];       // {ip_re, ip_im, bits(p), 0}

  float Cr[HC], Ci[HC], Br[HK], Bi[HK];

  // ---- load: lane reads its full row, keeps cols == w (mod 4) ----
  // R5-style divergent selects (cndmask) -- the proven-correct loader form.
  const size_t abase = (size_t)batch * NN * NN + (size_t)lane * NN;
  const float4* pAr = reinterpret_cast<const float4*>(A_r + abase);
  const float4* pAi = reinterpret_cast<const float4*>(A_i + abase);
#pragma unroll
  for (int j = 0; j < HC; ++j) {
    float4 v = pAr[j];                  // cols 4j .. 4j+3; keep element w
    Cr[j] = (w & 1) ? ((w & 2) ? v.w : v.y) : ((w & 2) ? v.z : v.x);
  }
#pragma unroll
  for (int j = 0; j < HC; ++j) {
    float4 v = pAi[j];
    Ci[j] = (w & 1) ? ((w & 2) ? v.w : v.y) : ((w & 2) ? v.z : v.x);
  }
  const size_t bbase = (size_t)batch * NN * KK + (size_t)lane * KK + (size_t)(HK * w);
  {
    float4 v = *reinterpret_cast<const float4*>(b_r + bbase);
    Br[0] = v.x; Br[1] = v.y; Br[2] = v.z; Br[3] = v.w;
    float4 u = *reinterpret_cast<const float4*>(b_i + bbase);
    Bi[0] = u.x; Bi[1] = u.y; Bi[2] = u.z; Bi[3] = u.w;
  }

  float invd_re = 0.f, invd_im = 0.f;
  int   mystep  = 0;
  bool  done    = false;

  for (int k = 0; k < NN; ++k) {
    const int owner = k & 3;
    const int buf   = k & 1;
    float m_re, m_im;
    int   p_loc;

    if (w == owner) {
      // ---- pivot: DPP argmax of |slot0|^2, lane idx in low 6 bits ----
      const float sc = Cr[0]*Cr[0] + Ci[0]*Ci[0];
      unsigned key = done ? (unsigned)lane
                          : ((__float_as_uint(sc) & ~63u) | (unsigned)lane);
      const int p = (int)(dpp_argmax64(key) & 63u);
      const float p_re = rlane(Cr[0], p);
      const float p_im = rlane(Ci[0], p);
      const float d    = p_re*p_re + p_im*p_im;
      float rd = __builtin_amdgcn_rcpf(d);
      rd = rd * (2.0f - d * rd);                  // 1 Newton step
      const float ip_re =  p_re * rd;
      const float ip_im = -p_im * rd;
      m_re = Cr[0]*ip_re - Ci[0]*ip_im;
      m_im = Cr[0]*ip_im + Ci[0]*ip_re;
      if (lane == p) {
        m_re = 0.f; m_im = 0.f;
        invd_re = ip_re; invd_im = ip_im;
        mystep = k; done = true;
      }
      mbuf[buf][lane] = float2{m_re, m_im};
      if (lane == 0)
        hdr[buf] = float4{ip_re, ip_im, __uint_as_float((unsigned)p), 0.f};
      p_loc = p;
    }
    __syncthreads();
    if (w != owner) {
      const float2 mv = mbuf[buf][lane];
      const float4 h  = hdr[buf];
      m_re = mv.x; m_im = mv.y;
      p_loc = (int)__float_as_uint(h.z);
      if (lane == p_loc) {
        invd_re = h.x; invd_im = h.y;
        mystep = k; done = true;
      }
    }
    // Re-uniform p after the divergent owner/non-owner merge.
    const int p = __builtin_amdgcn_readfirstlane(p_loc);

    // ---- A update (own columns, static indices, 4-block dead skipping) ----
    if (w == owner) {
      // live slots 0..hi; eliminate slot 0, rotate 1..hi -> 0..hi-1
      const int hi = 15 - (k >> 2);
#pragma unroll
      for (int blk = 0; blk < 4; ++blk) {
        const int j0 = (blk == 0) ? 1 : 4 * blk;
        if (hi >= j0) {
#pragma unroll
          for (int j = j0; j < 4 * (blk + 1); ++j) {
            const float sr = rlane(Cr[j], p);
            const float si = rlane(Ci[j], p);
            Cr[j-1] = __builtin_fmaf(-m_re, sr, __builtin_fmaf( m_im, si, Cr[j]));
            Ci[j-1] = __builtin_fmaf(-m_im, sr, __builtin_fmaf(-m_re, si, Ci[j]));
          }
        }
      }
    } else {
      const int e  = (k > w) ? ((k - w + 3) >> 2) : 0;
      const int hi = 15 - e;                      // update slots 0..hi in place
#pragma unroll
      for (int blk = 0; blk < 4; ++blk) {
        if (hi >= 4 * blk) {
#pragma unroll
          for (int j = 4 * blk; j < 4 * (blk + 1); ++j) {
            const float sr = rlane(Cr[j], p);
            const float si = rlane(Ci[j], p);
            Cr[j] = __builtin_fmaf(-m_re, sr, __builtin_fmaf( m_im, si, Cr[j]));
            Ci[j] = __builtin_fmaf(-m_im, sr, __builtin_fmaf(-m_re, si, Ci[j]));
          }
        }
      }
    }

    // ---- b update (own 4 columns, all waves) ----
#pragma unroll
    for (int c = 0; c < HK; ++c) {
      const float sr = rlane(Br[c], p);
      const float si = rlane(Bi[c], p);
      Br[c] = __builtin_fmaf(-m_re, sr, __builtin_fmaf( m_im, si, Br[c]));
      Bi[c] = __builtin_fmaf(-m_im, sr, __builtin_fmaf(-m_re, si, Bi[c]));
    }
  }

  // ---- x[mystep][c] = b[c] * invd ; lane writes its row, own 4 columns ----
  float xr[HK], xi[HK];
#pragma unroll
  for (int c = 0; c < HK; ++c) {
    xr[c] = Br[c]*invd_re - Bi[c]*invd_im;
    xi[c] = Br[c]*invd_im + Bi[c]*invd_re;
  }
  const size_t obase = (size_t)batch * NN * KK + (size_t)mystep * KK + (size_t)(HK * w);
  float* o_r = out + obase;
  float* o_i = out + (size_t)nbatch * NN * KK + obase;
  {
    float4 v; v.x = xr[0]; v.y = xr[1]; v.z = xr[2]; v.w = xr[3];
    *reinterpret_cast<float4*>(o_r) = v;
    float4 u; u.x = xi[0]; u.y = xi[1]; u.z = xi[2]; u.w = xi[3];
    *reinterpret_cast<float4*>(o_i) = u;
  }
}

extern "C" void kernel_launch(void* const* d_in, const int* in_sizes, int n_in,
                              void* d_out, int out_size, void* d_ws, size_t ws_size,
                              hipStream_t stream) {
  const float* A_r = (const float*)d_in[0];
  const float* A_i = (const float*)d_in[1];
  const float* b_r = (const float*)d_in[2];
  const float* b_i = (const float*)d_in[3];
  float* out = (float*)d_out;
  const int nbatch = in_sizes[0] / (NN * NN);  // 8192
  cgj_solve<<<nbatch, 256, 0, stream>>>(A_r, A_i, b_r, b_i, out, nbatch);
}